// Round 7
// baseline (4046.470 us; speedup 1.0000x reference)
//
#include <hip/hip_runtime.h>
#include <hip/hip_cooperative_groups.h>
#include <stdint.h>

namespace cg = cooperative_groups;
typedef unsigned long long ull;

static __device__ __forceinline__ ull packkey(float f, int v) {
    uint32_t u = __float_as_uint(f);
    u = (u & 0x80000000u) ? ~u : (u | 0x80000000u);
    return ((ull)u << 32) | (ull)(~(uint32_t)v);
}
static __device__ __forceinline__ int aload(const int* p) {
    return __hip_atomic_load(p, __ATOMIC_RELAXED, __HIP_MEMORY_SCOPE_AGENT);
}
static __device__ __forceinline__ ull aloadu(const ull* p) {
    return __hip_atomic_load(p, __ATOMIC_RELAXED, __HIP_MEMORY_SCOPE_AGENT);
}
static __device__ __forceinline__ void amax(ull* p, ull v) {
    __hip_atomic_fetch_max(p, v, __ATOMIC_RELAXED, __HIP_MEMORY_SCOPE_AGENT);
}
static __device__ __forceinline__ void aadd(int* p, int v) {
    __hip_atomic_fetch_add(p, v, __ATOMIC_RELAXED, __HIP_MEMORY_SCOPE_AGENT);
}

// phase helpers: broadcast max (centers) / release subs (all newly decided)
template<bool MR>
static __device__ __forceinline__ void do_max(int v, int K,
        const int* __restrict__ neighs, const float* __restrict__ hier,
        const int* __restrict__ mrow, ull* best) {
    ull kv = packkey(hier[v], v);
    if (MR) {
        if ((K & 3) == 0) {
            const int4* r4 = (const int4*)(mrow + (size_t)v * K);
            for (int q = 0; q < (K >> 2); q++) {
                int4 m = r4[q];
                if (m.x >= 0) amax(&best[m.x], kv);
                if (m.y >= 0) amax(&best[m.y], kv);
                if (m.z >= 0) amax(&best[m.z], kv);
                if (m.w >= 0) amax(&best[m.w], kv);
            }
        } else {
            for (int k = 0; k < K; k++) {
                int w = mrow[(size_t)v * K + k];
                if (w >= 0) amax(&best[w], kv);
            }
        }
    } else {
        for (int k = 0; k < K; k++) {
            int w = neighs[(size_t)v * K + k];
            if (w >= 0 && kv > packkey(hier[w], w)) amax(&best[w], kv);
        }
    }
}
template<bool MR>
static __device__ __forceinline__ void do_sub(int v, int K,
        const int* __restrict__ neighs, const float* __restrict__ hier,
        const int* __restrict__ mrow, int* pred) {
    if (MR) {
        if ((K & 3) == 0) {
            const int4* r4 = (const int4*)(mrow + (size_t)v * K);
            for (int q = 0; q < (K >> 2); q++) {
                int4 m = r4[q];
                if (m.x >= 0) aadd(&pred[m.x], -1);
                if (m.y >= 0) aadd(&pred[m.y], -1);
                if (m.z >= 0) aadd(&pred[m.z], -1);
                if (m.w >= 0) aadd(&pred[m.w], -1);
            }
        } else {
            for (int k = 0; k < K; k++) {
                int w = mrow[(size_t)v * K + k];
                if (w >= 0) aadd(&pred[w], -1);
            }
        }
    } else {
        ull kv = packkey(hier[v], v);
        for (int k = 0; k < K; k++) {
            int w = neighs[(size_t)v * K + k];
            if (w >= 0 && kv > packkey(hier[w], w)) aadd(&pred[w], -1);
        }
    }
}

// One fused cooperative kernel: build -> sync -> 2-phase rounds -> epilogue.
template<bool MR>
__global__ __launch_bounds__(256, 4)
void k_fused(const int* __restrict__ neighs, const float* __restrict__ hier,
             const int* __restrict__ row_splits,
             ull* best, int* pred, int* cnts, ull* segKeys, int* segIds, int* cidOf,
             int* mrow, int* sel_out, int* rs_out, int* clus_out,
             int V, int K, int NSEG, long E) {
    cg::grid_group grid = cg::this_grid();
    const int T = gridDim.x * blockDim.x;
    const int t = blockIdx.x * blockDim.x + threadIdx.x;
    const int lane = threadIdx.x & 63;

    // ---------------- build: masked rows + in-degree ----------------
    if ((K & 3) == 0) {
        long E4 = E >> 2;
        for (long q = t; q < E4; q += T) {
            long e = q << 2;
            int u = (int)(e / K);
            ull ku = packkey(hier[u], u);
            int4 nb = ((const int4*)neighs)[q];
            int m0 = (nb.x >= 0 && ku > packkey(hier[nb.x], nb.x)) ? nb.x : -1;
            int m1 = (nb.y >= 0 && ku > packkey(hier[nb.y], nb.y)) ? nb.y : -1;
            int m2 = (nb.z >= 0 && ku > packkey(hier[nb.z], nb.z)) ? nb.z : -1;
            int m3 = (nb.w >= 0 && ku > packkey(hier[nb.w], nb.w)) ? nb.w : -1;
            if (m0 >= 0) aadd(&pred[m0], 1);
            if (m1 >= 0) aadd(&pred[m1], 1);
            if (m2 >= 0) aadd(&pred[m2], 1);
            if (m3 >= 0) aadd(&pred[m3], 1);
            if (MR) ((int4*)mrow)[q] = make_int4(m0, m1, m2, m3);
        }
    } else {
        for (long e = t; e < E; e += T) {
            int u = (int)(e / K);
            int w = neighs[e];
            int m = (w >= 0 && packkey(hier[u], u) > packkey(hier[w], w)) ? w : -1;
            if (m >= 0) aadd(&pred[m], 1);
            if (MR) mrow[e] = m;
        }
    }
    grid.sync();

    // ---------------- two-phase synchronous rounds ----------------
    // round r: [detect pred==0 -> centers max] sync [detect best!=0 -> all decided sub] sync
    const int v0 = t, v1 = t + T;
    const bool own0 = v0 < V, own1 = v1 < V;
    int st0 = own0 ? 0 : 3, st1 = own1 ? 0 : 3;   // 0 undec, 1 cen-pend, 2 abs-pend, 3 done
    int* doneCnt = cnts + 32;

    for (int round = 0; round < V; ++round) {
        if (st0 == 0 && aload(&pred[v0]) == 0) st0 = 1;
        if (st1 == 0 && aload(&pred[v1]) == 0) st1 = 1;
        if (st0 == 1) do_max<MR>(v0, K, neighs, hier, mrow, best);
        if (st1 == 1) do_max<MR>(v1, K, neighs, hier, mrow, best);
        grid.sync();

        if (st0 == 0 && aloadu(&best[v0]) != 0ull) st0 = 2;
        if (st1 == 0 && aloadu(&best[v1]) != 0ull) st1 = 2;
        bool n0 = (st0 == 1 || st0 == 2);
        bool n1 = (st1 == 1 || st1 == 2);
        if (n0) { do_sub<MR>(v0, K, neighs, hier, mrow, pred); st0 = 3; }
        if (n1) { do_sub<MR>(v1, K, neighs, hier, mrow, pred); st1 = 3; }
        ull b0 = __ballot(n0), b1 = __ballot(n1);
        if (lane == 0 && (b0 | b1))
            aadd(doneCnt, __popcll(b0) + __popcll(b1));
        grid.sync();

        if (aload(doneCnt) >= V) break;
    }

    // ---------------- epilogue: compact -> rs -> rank -> assign ----------------
    if (own0 && aloadu(&best[v0]) == 0ull) {
        int s = 0; while (s + 1 < NSEG && v0 >= row_splits[s + 1]) s++;
        int p = __hip_atomic_fetch_add(&cnts[s], 1, __ATOMIC_RELAXED, __HIP_MEMORY_SCOPE_AGENT);
        int base = row_splits[s];
        segKeys[base + p] = packkey(hier[v0], v0);
        segIds[base + p] = v0;
    }
    if (own1 && aloadu(&best[v1]) == 0ull) {
        int s = 0; while (s + 1 < NSEG && v1 >= row_splits[s + 1]) s++;
        int p = __hip_atomic_fetch_add(&cnts[s], 1, __ATOMIC_RELAXED, __HIP_MEMORY_SCOPE_AGENT);
        int base = row_splits[s];
        segKeys[base + p] = packkey(hier[v1], v1);
        segIds[base + p] = v1;
    }
    grid.sync();

    if (t == 0) {
        int acc = 0;
        rs_out[0] = 0;
        for (int s = 0; s < NSEG; s++) {
            cnts[16 + s] = acc;
            acc += cnts[s];
            rs_out[s + 1] = acc;
        }
    }
    grid.sync();

    // rank: one wave per center slot (coalesced, no atomics)
    const int NW = T >> 6;
    const int wv = t >> 6;
    for (int slot = wv; slot < V; slot += NW) {
        int s = 0; while (s + 1 < NSEG && slot >= row_splits[s + 1]) s++;
        int base = row_splits[s];
        int j = slot - base;
        int cnt = cnts[s];
        if (j >= cnt) continue;
        ull mk = segKeys[slot];
        int r = 0;
        for (int i = lane; i < cnt; i += 64) r += (segKeys[base + i] > mk) ? 1 : 0;
        for (int off = 32; off; off >>= 1) r += __shfl_down(r, off);
        if (lane == 0) {
            int cid = cnts[16 + s] + r;
            int vv = segIds[slot];
            cidOf[vv] = cid;
            sel_out[cid] = vv;
        }
    }
    grid.sync();

    if (own0) {
        ull b = best[v0];
        clus_out[v0] = (b == 0ull) ? cidOf[v0] : cidOf[(int)(~(uint32_t)(b & 0xFFFFFFFFull))];
    }
    if (own1) {
        ull b = best[v1];
        clus_out[v1] = (b == 0ull) ? cidOf[v1] : cidOf[(int)(~(uint32_t)(b & 0xFFFFFFFFull))];
    }
}

extern "C" void kernel_launch(void* const* d_in, const int* in_sizes, int n_in,
                              void* d_out, int out_size, void* d_ws, size_t ws_size,
                              hipStream_t stream) {
    const int*   neighs     = (const int*)d_in[0];
    const float* hier       = (const float*)d_in[1];
    const int*   row_splits = (const int*)d_in[2];

    const int V    = in_sizes[1];
    const int K    = in_sizes[0] / V;
    const int NSEG = in_sizes[2] - 1;
    const long E   = (long)V * (long)K;

    int* out      = (int*)d_out;
    int* sel_out  = out;
    int* rs_out   = out + V;
    int* clus_out = out + V + NSEG + 1;

    // ws: [best 8V][pred 4V][cnts 256B][segKeys 8V][segIds 4V][cidOf 4V][mrow 4E]
    char* w = (char*)d_ws;
    ull* best    = (ull*)(w);
    int* pred    = (int*)(w + (size_t)8 * V);
    int* cnts    = (int*)(w + (size_t)12 * V);
    ull* segKeys = (ull*)(w + (size_t)12 * V + 256);
    int* segIds  = (int*)(w + (size_t)20 * V + 256);
    int* cidOf   = (int*)(w + (size_t)24 * V + 256);
    int* mrow    = (int*)(w + (size_t)28 * V + 256);

    const size_t needMR = (size_t)28 * V + 256 + (size_t)4 * E;
    const bool mr = ws_size >= needMR;

    (void)hipMemsetAsync(w, 0, (size_t)12 * V + 256, stream);     // best, pred, cnts
    (void)hipMemsetAsync(sel_out, 0xFF, (size_t)4 * V, stream);   // sel padded with -1

    int Vv = V, Kk = K, Ns = NSEG;
    long Ee = E;
    void* args[] = {
        (void*)&neighs, (void*)&hier, (void*)&row_splits,
        (void*)&best, (void*)&pred, (void*)&cnts, (void*)&segKeys, (void*)&segIds,
        (void*)&cidOf, (void*)&mrow, (void*)&sel_out, (void*)&rs_out, (void*)&clus_out,
        (void*)&Vv, (void*)&Kk, (void*)&Ns, (void*)&Ee
    };
    // 1024 blocks x 256 = 262144 threads, 4 blocks/CU co-resident (launch_bounds(256,4))
    if (mr) {
        (void)hipLaunchCooperativeKernel((void*)k_fused<true>, dim3(1024), dim3(256),
                                         args, 0, stream);
    } else {
        (void)hipLaunchCooperativeKernel((void*)k_fused<false>, dim3(1024), dim3(256),
                                         args, 0, stream);
    }
}